// Round 5
// baseline (189.124 us; speedup 1.0000x reference)
//
#include <hip/hip_runtime.h>

typedef __attribute__((ext_vector_type(8))) short bf16x8;
typedef __attribute__((ext_vector_type(16))) float f32x16;
typedef __attribute__((ext_vector_type(4))) float f32x4;

__device__ inline unsigned short f2bf_rne(float x) {
  unsigned u = __float_as_uint(x);
  unsigned r = u + 0x7FFFu + ((u >> 16) & 1u);
  return (unsigned short)(r >> 16);
}
__device__ inline float bf2f(unsigned short h) {
  return __uint_as_float(((unsigned)h) << 16);
}

// ---------- P0: mprep[i,j] = mask[i,j] / deg[i] ----------
__global__ __launch_bounds__(256) void deg_mprep_kernel(const int* __restrict__ mask,
                                                        float* __restrict__ mprep) {
  int i = blockIdx.x, t = threadIdx.x;
  int sum = 0;
  for (int j = t; j < 768; j += 256) sum += mask[i*768 + j];
  for (int off = 32; off; off >>= 1) sum += __shfl_down(sum, off, 64);
  __shared__ int part[4];
  __shared__ float inv_s;
  if ((t & 63) == 0) part[t >> 6] = sum;
  __syncthreads();
  if (t == 0) inv_s = 1.0f / (float)(part[0] + part[1] + part[2] + part[3]);
  __syncthreads();
  float inv = inv_s;
  for (int j = t; j < 768; j += 256) mprep[i*768 + j] = (float)mask[i*768 + j] * inv;
}

// ---------- P0b: enc -> bf16 packed, hop-invariant, run ONCE ----------
// encpk[u32 g] : g = ij*8 + e2, packs k=2*e2, 2*e2+1 of enc[ij]
__global__ __launch_bounds__(256) void encpk_kernel(const float* __restrict__ enc,
                                                    unsigned* __restrict__ encpk) {
  int h = blockIdx.x * 256 + threadIdx.x;       // < 2359296
  f32x4 v = *(const f32x4*)(enc + (size_t)h * 4);
  unsigned lo = (unsigned)f2bf_rne(v[0]) | ((unsigned)f2bf_rne(v[1]) << 16);
  unsigned hi = (unsigned)f2bf_rne(v[2]) | ((unsigned)f2bf_rne(v[3]) << 16);
  uint2 o; o.x = lo; o.y = hi;
  *(uint2*)(encpk + (size_t)h * 2) = o;
}

// ---------- P1: per-node A (hi/lo bf16, interleaved b) and Zej (fp32) ----------
__global__ __launch_bounds__(256) void prep_kernel(const float* __restrict__ seq,
                                                   const float* __restrict__ W1,
                                                   const float* __restrict__ b1,
                                                   unsigned* __restrict__ apk2,
                                                   float* __restrict__ zej) {
  int bi = blockIdx.x;  // b*768 + n
  int b = (bi >= 768) ? 1 : 0;
  int n = bi - b * 768;
  __shared__ float sq[64];
  if (threadIdx.x < 64) sq[threadIdx.x] = seq[bi*64 + threadIdx.x];
  __syncthreads();
  int c = threadIdx.x;
  if (c < 160) {
    float accA = 0.f, accZ = 0.f;
    if (c < 144) {
      accA = b1[c];
#pragma unroll
      for (int u = 0; u < 64; ++u) accA = fmaf(sq[u], W1[u*144 + c], accA);
#pragma unroll
      for (int u = 0; u < 64; ++u) accZ = fmaf(sq[u], W1[(64 + u)*144 + c], accZ);
    }
    unsigned short hi = f2bf_rne(accA);
    unsigned short lo = f2bf_rne(accA - bf2f(hi));
    if (c >= 144) { hi = 0; lo = 0; }
    apk2[(n*160 + c)*2 + b] = (unsigned)hi | ((unsigned)lo << 16);
    zej[bi*160 + c] = accZ;
  }
}

// ---------- P2: W1 enc-rows as A-operand fragments + padded w2 ----------
__global__ __launch_bounds__(256) void wpk_kernel(const float* __restrict__ W1,
                                                  const float* __restrict__ W2,
                                                  unsigned* __restrict__ wpk,
                                                  float* __restrict__ w2pad) {
  int g = blockIdx.x*256 + threadIdx.x;
  if (g < 1280) {
    int ew = g & 3;
    int l = (g >> 2) & 63;
    int t = g >> 8;                 // c-tile 0..4
    int c = t*32 + (l & 31);
    unsigned short h[2];
#pragma unroll
    for (int q = 0; q < 2; ++q) {
      int e = ew*2 + q;
      int koff = (l >> 5)*8 + e;    // k-channel 0..15
      float v = (c < 144) ? W1[(128 + koff)*144 + c] : 0.f;
      h[q] = f2bf_rne(v);
    }
    wpk[g] = (unsigned)h[0] | ((unsigned)h[1] << 16);
  } else if (g < 1440) {
    int c = g - 1280;
    w2pad[c] = (c < 144) ? W2[c] : 0.f;
  }
}

// ---------- edge kernel: 5 waves = 5 c-tiles; ring prefetch; 4 MFMA/i ----------
__global__ __launch_bounds__(320, 3) void edge_kernel(
    const unsigned* __restrict__ encpk, const unsigned* __restrict__ apk2,
    const float* __restrict__ zej, const unsigned* __restrict__ wpk,
    const float* __restrict__ w2pad, const float* __restrict__ b2p,
    const float* __restrict__ mprep, float* __restrict__ s_out) {
  const int tid = threadIdx.x;
  const int lane = tid & 63;
  const int w = tid >> 6;          // c-tile 0..4
  const int jb = blockIdx.x;       // 0..23
  const int i0 = blockIdx.y * 12;  // 64 i-blocks
  const int l31 = lane & 31, lh = lane >> 5;
  const int jglob = jb*32 + l31;

  bf16x8 wfrag = ((const bf16x8*)wpk)[w*64 + lane];

  float w2own[16];
#pragma unroll
  for (int r = 0; r < 16; ++r)
    w2own[r] = w2pad[w*32 + (r & 3) + 8*(r >> 2) + 4*lh];

  // Zej C-inits (fp32, C/D layout), per batch
  f32x16 Cz0, Cz1;
#pragma unroll
  for (int q = 0; q < 4; ++q) {
    f32x4 z0 = *(const f32x4*)&zej[(0*768 + jglob)*160 + w*32 + 4*lh + 8*q];
    f32x4 z1 = *(const f32x4*)&zej[(768   + jglob)*160 + w*32 + 4*lh + 8*q];
#pragma unroll
    for (int m = 0; m < 4; ++m) { Cz0[q*4 + m] = z0[m]; Cz1[q*4 + m] = z1[m]; }
  }

  bf16x8 ones;
#pragma unroll
  for (int e = 0; e < 8; ++e) ones[e] = 0;
  if (lh == 0) { ones[0] = (short)0x3F80; ones[1] = (short)0x3F80; }

  __shared__ float pdot[5][2][12][32];
  __shared__ float scomb[192];
  const float b2 = *b2p;

  const bf16x8* encp = (const bf16x8*)encpk;
  const uint2* apkp = (const uint2*)apk2;

  // prefetch ring: 6 i's ahead
  bf16x8 enc_r[6];
  uint2 apk_r[6];
#pragma unroll
  for (int p = 0; p < 6; ++p) {
    enc_r[p] = encp[((size_t)(i0 + p)*768 + jglob)*2 + lh];
    apk_r[p] = (lh == 0) ? apkp[(i0 + p)*160 + w*32 + l31] : make_uint2(0u, 0u);
  }

  float sacc_t = 0.f;
#pragma unroll 1
  for (int seg = 0; seg < 2; ++seg) {
#pragma unroll
    for (int il = 0; il < 6; ++il) {
      const int i = i0 + seg*6 + il;
      bf16x8 encf = enc_r[il];
      uint2 av = apk_r[il];
      if (seg == 0) {
        enc_r[il] = encp[((size_t)(i + 6)*768 + jglob)*2 + lh];
        apk_r[il] = (lh == 0) ? apkp[(i + 6)*160 + w*32 + l31] : make_uint2(0u, 0u);
      }
      f32x16 Ce0 = __builtin_amdgcn_mfma_f32_32x32x16_bf16(wfrag, encf, Cz0, 0, 0, 0);
      f32x16 Ce1 = __builtin_amdgcn_mfma_f32_32x32x16_bf16(wfrag, encf, Cz1, 0, 0, 0);

      bf16x8 af0, af1;
#pragma unroll
      for (int e = 0; e < 8; ++e) { af0[e] = 0; af1[e] = 0; }
      af0[0] = (short)(av.x & 0xFFFFu); af0[1] = (short)(av.x >> 16);
      af1[0] = (short)(av.y & 0xFFFFu); af1[1] = (short)(av.y >> 16);

      f32x16 Cb0 = __builtin_amdgcn_mfma_f32_32x32x16_bf16(af0, ones, Ce0, 0, 0, 0);
      f32x16 Cb1 = __builtin_amdgcn_mfma_f32_32x32x16_bf16(af1, ones, Ce1, 0, 0, 0);

      float dp0 = 0.f, dp1 = 0.f;
#pragma unroll
      for (int r = 0; r < 16; ++r) {
        float z0 = Cb0[r], z1 = Cb1[r];
        float h0 = fmaxf(z0, 0.01f*z0);
        float h1 = fmaxf(z1, 0.01f*z1);
        dp0 = fmaf(h0, w2own[r], dp0);
        dp1 = fmaf(h1, w2own[r], dp1);
      }
      pdot[w][lh][il*2 + 0][l31] = dp0;
      pdot[w][lh][il*2 + 1][l31] = dp1;
    }
    __syncthreads();
    if (tid < 192) {
      const int j = tid & 31, g6 = tid >> 5;   // g6 0..5
      const int b = g6 & 1;
      const int u1 = g6, u2 = g6 + 6;          // units: il*2+b
      float s1 = 0.f, s2 = 0.f;
#pragma unroll
      for (int w5 = 0; w5 < 5; ++w5) {
        s1 += pdot[w5][0][u1][j] + pdot[w5][1][u1][j];
        s2 += pdot[w5][0][u2][j] + pdot[w5][1][u2][j];
      }
      const int i1 = i0 + seg*6 + (g6 >> 1);
      const int i2 = i1 + 3;
      float wv1 = s1 + b2; wv1 = fmaxf(wv1, 0.01f*wv1);
      float wv2 = s2 + b2; wv2 = fmaxf(wv2, 0.01f*wv2);
      sacc_t = fmaf(mprep[i1*768 + jb*32 + j], wv1, sacc_t);
      sacc_t = fmaf(mprep[i2*768 + jb*32 + j], wv2, sacc_t);
      (void)b;
    }
    __syncthreads();
  }
  if (tid < 192) scomb[tid] = sacc_t;
  __syncthreads();
  if (tid < 64) {
    const int b = tid >> 5, j = tid & 31;
    float tot = scomb[b*32 + j] + scomb[(b + 2)*32 + j] + scomb[(b + 4)*32 + j];
    atomicAdd(&s_out[b*768 + jb*32 + j], tot);
  }
}

// ---------- seq' = s * seq ----------
__global__ __launch_bounds__(256) void scale_kernel(const float* __restrict__ s,
                                                    const float* __restrict__ seq_in,
                                                    float* __restrict__ seq_out) {
  int idx = blockIdx.x * 256 + threadIdx.x;
  seq_out[idx] = s[idx >> 6] * seq_in[idx];
}

extern "C" void kernel_launch(void* const* d_in, const int* in_sizes, int n_in,
                              void* d_out, int out_size, void* d_ws, size_t ws_size,
                              hipStream_t stream) {
  const float* seq  = (const float*)d_in[0];
  const float* enc  = (const float*)d_in[1];
  const int*   mask = (const int*)d_in[2];
  const float* W11  = (const float*)d_in[3];
  const float* b11  = (const float*)d_in[4];
  const float* W12  = (const float*)d_in[5];
  const float* b12  = (const float*)d_in[6];
  const float* W21  = (const float*)d_in[7];
  const float* b21  = (const float*)d_in[8];
  const float* W22  = (const float*)d_in[9];
  const float* b22  = (const float*)d_in[10];
  float* out = (float*)d_out;

  float* ws = (float*)d_ws;
  size_t off = 0;
  float* mprep = ws + off;                 off += 768*768;
  unsigned* apk2 = (unsigned*)(ws + off);  off += 2*768*160;
  float* zej = ws + off;                   off += 2*768*160;
  unsigned* wpk = (unsigned*)(ws + off);   off += 1280;
  float* w2pad = ws + off;                 off += 160;
  float* sacc  = ws + off;                 off += 2*768;
  float* seq_mid = ws + off;               off += 2*768*64;
  unsigned* encpk = (unsigned*)(ws + off); off += 768*768*8;

  deg_mprep_kernel<<<768, 256, 0, stream>>>(mask, mprep);
  encpk_kernel<<<9216, 256, 0, stream>>>(enc, encpk);

  // hop 1
  prep_kernel<<<1536, 256, 0, stream>>>(seq, W11, b11, apk2, zej);
  wpk_kernel<<<6, 256, 0, stream>>>(W11, W12, wpk, w2pad);
  hipMemsetAsync(sacc, 0, 1536*sizeof(float), stream);
  edge_kernel<<<dim3(24, 64), 320, 0, stream>>>(encpk, apk2, zej, wpk, w2pad, b12, mprep, sacc);
  scale_kernel<<<384, 256, 0, stream>>>(sacc, seq, seq_mid);

  // hop 2
  prep_kernel<<<1536, 256, 0, stream>>>(seq_mid, W21, b21, apk2, zej);
  wpk_kernel<<<6, 256, 0, stream>>>(W21, W22, wpk, w2pad);
  hipMemsetAsync(sacc, 0, 1536*sizeof(float), stream);
  edge_kernel<<<dim3(24, 64), 320, 0, stream>>>(encpk, apk2, zej, wpk, w2pad, b22, mprep, sacc);
  scale_kernel<<<384, 256, 0, stream>>>(sacc, seq_mid, out);
}

// Round 7
// 124.826 us; speedup vs baseline: 1.5151x; 1.5151x over previous
//
#include <hip/hip_runtime.h>

typedef __attribute__((ext_vector_type(8))) short bf16x8;
typedef __attribute__((ext_vector_type(16))) float f32x16;
typedef __attribute__((ext_vector_type(4))) float f32x4;

__device__ inline unsigned short f2bf_rne(float x) {
  unsigned u = __float_as_uint(x);
  unsigned r = u + 0x7FFFu + ((u >> 16) & 1u);
  return (unsigned short)(r >> 16);
}
__device__ inline float bf2f(unsigned short h) {
  return __uint_as_float(((unsigned)h) << 16);
}

// ---------- P0: mprep[i,j] = mask[i,j] / deg[i] ----------
__global__ __launch_bounds__(256) void deg_mprep_kernel(const int* __restrict__ mask,
                                                        float* __restrict__ mprep) {
  int i = blockIdx.x, t = threadIdx.x;
  int sum = 0;
  for (int j = t; j < 768; j += 256) sum += mask[i*768 + j];
  for (int off = 32; off; off >>= 1) sum += __shfl_down(sum, off, 64);
  __shared__ int part[4];
  __shared__ float inv_s;
  if ((t & 63) == 0) part[t >> 6] = sum;
  __syncthreads();
  if (t == 0) inv_s = 1.0f / (float)(part[0] + part[1] + part[2] + part[3]);
  __syncthreads();
  float inv = inv_s;
  for (int j = t; j < 768; j += 256) mprep[i*768 + j] = (float)mask[i*768 + j] * inv;
}

// ---------- P0b: enc -> bf16 packed (hop-invariant, run once) ----------
__global__ __launch_bounds__(256) void encpk_kernel(const float* __restrict__ enc,
                                                    unsigned* __restrict__ encpk) {
  int h = blockIdx.x * 256 + threadIdx.x;       // < 2359296
  f32x4 v = *(const f32x4*)(enc + (size_t)h * 4);
  unsigned lo = (unsigned)f2bf_rne(v[0]) | ((unsigned)f2bf_rne(v[1]) << 16);
  unsigned hi = (unsigned)f2bf_rne(v[2]) | ((unsigned)f2bf_rne(v[3]) << 16);
  uint2 o; o.x = lo; o.y = hi;
  *(uint2*)(encpk + (size_t)h * 2) = o;
}

// ---------- P1: per-node A (hi/lo bf16, b-interleaved) and Zej (fp32) ----------
__global__ __launch_bounds__(256) void prep_kernel(const float* __restrict__ seq,
                                                   const float* __restrict__ W1,
                                                   const float* __restrict__ b1,
                                                   unsigned* __restrict__ apk2,
                                                   float* __restrict__ zej) {
  int bi = blockIdx.x;  // b*768 + n
  int b = (bi >= 768) ? 1 : 0;
  int n = bi - b * 768;
  __shared__ float sq[64];
  if (threadIdx.x < 64) sq[threadIdx.x] = seq[bi*64 + threadIdx.x];
  __syncthreads();
  int c = threadIdx.x;
  if (c < 160) {
    float accA = 0.f, accZ = 0.f;
    if (c < 144) {
      accA = b1[c];
#pragma unroll
      for (int u = 0; u < 64; ++u) accA = fmaf(sq[u], W1[u*144 + c], accA);
#pragma unroll
      for (int u = 0; u < 64; ++u) accZ = fmaf(sq[u], W1[(64 + u)*144 + c], accZ);
    }
    unsigned short hi = f2bf_rne(accA);
    unsigned short lo = f2bf_rne(accA - bf2f(hi));
    if (c >= 144) { hi = 0; lo = 0; }
    apk2[(n*160 + c)*2 + b] = (unsigned)hi | ((unsigned)lo << 16);
    zej[bi*160 + c] = accZ;
  }
}

// ---------- P2: W1 enc-rows as A-operand fragments + padded w2 ----------
__global__ __launch_bounds__(256) void wpk_kernel(const float* __restrict__ W1,
                                                  const float* __restrict__ W2,
                                                  unsigned* __restrict__ wpk,
                                                  float* __restrict__ w2pad) {
  int g = blockIdx.x*256 + threadIdx.x;
  if (g < 1280) {
    int ew = g & 3;
    int l = (g >> 2) & 63;
    int t = g >> 8;                 // c-tile 0..4
    int c = t*32 + (l & 31);
    unsigned short h[2];
#pragma unroll
    for (int q = 0; q < 2; ++q) {
      int e = ew*2 + q;
      int koff = (l >> 5)*8 + e;    // k-channel 0..15
      float v = (c < 144) ? W1[(128 + koff)*144 + c] : 0.f;
      h[q] = f2bf_rne(v);
    }
    wpk[g] = (unsigned)h[0] | ((unsigned)h[1] << 16);
  } else if (g < 1440) {
    int c = g - 1280;
    w2pad[c] = (c < 144) ? W2[c] : 0.f;
  }
}

// ---------- edge kernel: per-wave global_load_lds enc ring + apk reg ring ----------
__global__ __launch_bounds__(320, 3) void edge_kernel(
    const unsigned* __restrict__ encpk, const uint2* __restrict__ apkp,
    const float* __restrict__ zej, const unsigned* __restrict__ wpk,
    const float* __restrict__ w2pad, const float* __restrict__ b2p,
    const float* __restrict__ mprep, float* __restrict__ s_out) {
  const int tid = threadIdx.x;
  const int lane = tid & 63;
  const int w = tid >> 6;          // c-tile 0..4
  const int jb = blockIdx.x;       // 0..23
  const int i0 = blockIdx.y * 12;  // 64 i-blocks
  const int l31 = lane & 31, lh = lane >> 5;
  const int jglob = jb*32 + l31;

  bf16x8 wfrag = ((const bf16x8*)wpk)[w*64 + lane];

  float w2own[16];
#pragma unroll
  for (int r = 0; r < 16; ++r)
    w2own[r] = w2pad[w*32 + (r & 3) + 8*(r >> 2) + 4*lh];

  // Zej C-init (fp32, C/D layout): Cz0 = b0, dz = b1 - b0
  f32x16 Cz0;
  float dz[16];
#pragma unroll
  for (int q = 0; q < 4; ++q) {
    f32x4 z0 = *(const f32x4*)&zej[(0*768 + jglob)*160 + w*32 + 4*lh + 8*q];
    f32x4 z1 = *(const f32x4*)&zej[(768   + jglob)*160 + w*32 + 4*lh + 8*q];
#pragma unroll
    for (int m = 0; m < 4; ++m) { Cz0[q*4 + m] = z0[m]; dz[q*4 + m] = z1[m] - z0[m]; }
  }

  bf16x8 ones;
#pragma unroll
  for (int e = 0; e < 8; ++e) ones[e] = 0;
  if (lh == 0) { ones[0] = (short)0x3F80; ones[1] = (short)0x3F80; }

  __shared__ float pdot[5][2][24][32];             // 30 KB
  __shared__ float scomb[256];                     // 1 KB
  __shared__ __align__(16) char lds_enc[5][4][1024]; // 20 KB: PER-WAVE rings
  const float b2 = *b2p;

  // drain prologue vmem so steady-state vmcnt counts are exact
  asm volatile("s_waitcnt vmcnt(0)" ::: "memory");
  __builtin_amdgcn_sched_barrier(0);

  uint2 apkv[4];

  // source per lane = exactly the 16B this lane will read back (write order == read order)
#define GLD_ENC(I, SLOT)                                                        \
  __builtin_amdgcn_global_load_lds(                                            \
      (const __attribute__((address_space(1))) unsigned*)(encpk +              \
          (size_t)(i0 + (I))*6144 + jb*256 + l31*8 + lh*4),                     \
      (__attribute__((address_space(3))) unsigned*)&lds_enc[w][SLOT][0], 16, 0, 0)

  // prologue: issue pairs 0..2 (2 vmem ops per pair: enc DMA + apk reg load)
  GLD_ENC(0, 0); apkv[0] = apkp[(i0 + 0)*160 + w*32 + l31];
  GLD_ENC(1, 1); apkv[1] = apkp[(i0 + 1)*160 + w*32 + l31];
  GLD_ENC(2, 2); apkv[2] = apkp[(i0 + 2)*160 + w*32 + l31];

  auto body = [&](int il, int slot) {
    bf16x8 encf = *(const bf16x8*)(&lds_enc[w][slot][lane*16]);
    uint2 av = apkv[slot];

    f32x16 Ce = __builtin_amdgcn_mfma_f32_32x32x16_bf16(wfrag, encf, Cz0, 0, 0, 0);
    f32x16 C1;
#pragma unroll
    for (int r = 0; r < 16; ++r) C1[r] = Ce[r] + dz[r];

    bf16x8 af0, af1;
#pragma unroll
    for (int e = 0; e < 8; ++e) { af0[e] = 0; af1[e] = 0; }
    af0[0] = (short)(av.x & 0xFFFFu); af0[1] = (short)(av.x >> 16);
    af1[0] = (short)(av.y & 0xFFFFu); af1[1] = (short)(av.y >> 16);

    f32x16 Cb0 = __builtin_amdgcn_mfma_f32_32x32x16_bf16(af0, ones, Ce, 0, 0, 0);
    f32x16 Cb1 = __builtin_amdgcn_mfma_f32_32x32x16_bf16(af1, ones, C1, 0, 0, 0);

    float t0[4] = {0.f, 0.f, 0.f, 0.f}, t1[4] = {0.f, 0.f, 0.f, 0.f};
#pragma unroll
    for (int r = 0; r < 16; ++r) {
      float z0 = Cb0[r], z1 = Cb1[r];
      float h0 = fmaxf(z0, 0.01f*z0);
      float h1 = fmaxf(z1, 0.01f*z1);
      t0[r & 3] = fmaf(h0, w2own[r], t0[r & 3]);
      t1[r & 3] = fmaf(h1, w2own[r], t1[r & 3]);
    }
    pdot[w][lh][il*2 + 0][l31] = (t0[0] + t0[1]) + (t0[2] + t0[3]);
    pdot[w][lh][il*2 + 1][l31] = (t1[0] + t1[1]) + (t1[2] + t1[3]);
  };

#define STEP(IL, VM)                                                            \
  do {                                                                          \
    if ((IL) < 9) {                                                             \
      GLD_ENC((IL) + 3, ((IL) + 3) & 3);                                        \
      apkv[((IL) + 3) & 3] = apkp[(i0 + (IL) + 3)*160 + w*32 + l31];            \
    }                                                                           \
    asm volatile("s_waitcnt vmcnt(" #VM ")" ::: "memory");                      \
    __builtin_amdgcn_sched_barrier(0);                                          \
    body((IL), (IL) & 3);                                                       \
  } while (0)

  STEP(0, 6);  STEP(1, 6);  STEP(2, 6);  STEP(3, 6);
  STEP(4, 6);  STEP(5, 6);  STEP(6, 6);  STEP(7, 6);
  STEP(8, 6);  STEP(9, 4);  STEP(10, 2); STEP(11, 0);
#undef STEP
#undef GLD_ENC

  __syncthreads();

  if (tid < 256) {
    const int j = tid & 31, isub = (tid >> 5) & 3, b = tid >> 7;
    float sacc_t = 0.f;
#pragma unroll
    for (int k3 = 0; k3 < 3; ++k3) {
      const int il = isub + k3*4;
      const int unit = il*2 + b;
      float sum = 0.f;
#pragma unroll
      for (int w5 = 0; w5 < 5; ++w5)
        sum += pdot[w5][0][unit][j] + pdot[w5][1][unit][j];
      float wv = sum + b2;
      wv = fmaxf(wv, 0.01f*wv);
      sacc_t = fmaf(mprep[(i0 + il)*768 + jb*32 + j], wv, sacc_t);
    }
    scomb[tid] = sacc_t;   // scomb[b*128 + isub*32 + j]
  }
  __syncthreads();
  if (tid < 64) {
    const int b = tid >> 5, j = tid & 31;
    float tot = 0.f;
#pragma unroll
    for (int isub = 0; isub < 4; ++isub)
      tot += scomb[b*128 + isub*32 + j];
    atomicAdd(&s_out[b*768 + jb*32 + j], tot);
  }
}

// ---------- seq' = s * seq ----------
__global__ __launch_bounds__(256) void scale_kernel(const float* __restrict__ s,
                                                    const float* __restrict__ seq_in,
                                                    float* __restrict__ seq_out) {
  int idx = blockIdx.x * 256 + threadIdx.x;
  seq_out[idx] = s[idx >> 6] * seq_in[idx];
}

extern "C" void kernel_launch(void* const* d_in, const int* in_sizes, int n_in,
                              void* d_out, int out_size, void* d_ws, size_t ws_size,
                              hipStream_t stream) {
  const float* seq  = (const float*)d_in[0];
  const float* enc  = (const float*)d_in[1];
  const int*   mask = (const int*)d_in[2];
  const float* W11  = (const float*)d_in[3];
  const float* b11  = (const float*)d_in[4];
  const float* W12  = (const float*)d_in[5];
  const float* b12  = (const float*)d_in[6];
  const float* W21  = (const float*)d_in[7];
  const float* b21  = (const float*)d_in[8];
  const float* W22  = (const float*)d_in[9];
  const float* b22  = (const float*)d_in[10];
  float* out = (float*)d_out;

  float* ws = (float*)d_ws;
  size_t off = 0;
  float* mprep = ws + off;                 off += 768*768;
  unsigned* apk2 = (unsigned*)(ws + off);  off += 2*768*160;
  float* zej = ws + off;                   off += 2*768*160;
  unsigned* wpk = (unsigned*)(ws + off);   off += 1280;
  float* w2pad = ws + off;                 off += 160;
  float* sacc  = ws + off;                 off += 2*768;
  float* seq_mid = ws + off;               off += 2*768*64;
  unsigned* encpk = (unsigned*)(ws + off); off += 768*768*8;

  deg_mprep_kernel<<<768, 256, 0, stream>>>(mask, mprep);
  encpk_kernel<<<9216, 256, 0, stream>>>(enc, encpk);

  // hop 1
  prep_kernel<<<1536, 256, 0, stream>>>(seq, W11, b11, apk2, zej);
  wpk_kernel<<<6, 256, 0, stream>>>(W11, W12, wpk, w2pad);
  hipMemsetAsync(sacc, 0, 1536*sizeof(float), stream);
  edge_kernel<<<dim3(24, 64), 320, 0, stream>>>(encpk, (const uint2*)apk2, zej, wpk,
                                                w2pad, b12, mprep, sacc);
  scale_kernel<<<384, 256, 0, stream>>>(sacc, seq, seq_mid);

  // hop 2
  prep_kernel<<<1536, 256, 0, stream>>>(seq_mid, W21, b21, apk2, zej);
  wpk_kernel<<<6, 256, 0, stream>>>(W21, W22, wpk, w2pad);
  hipMemsetAsync(sacc, 0, 1536*sizeof(float), stream);
  edge_kernel<<<dim3(24, 64), 320, 0, stream>>>(encpk, (const uint2*)apk2, zej, wpk,
                                                w2pad, b22, mprep, sacc);
  scale_kernel<<<384, 256, 0, stream>>>(sacc, seq_mid, out);
}

// Round 8
// 116.336 us; speedup vs baseline: 1.6257x; 1.0730x over previous
//
#include <hip/hip_runtime.h>

typedef __attribute__((ext_vector_type(8))) short bf16x8;
typedef __attribute__((ext_vector_type(16))) float f32x16;
typedef __attribute__((ext_vector_type(4))) float f32x4;

__device__ inline unsigned short f2bf_rne(float x) {
  unsigned u = __float_as_uint(x);
  unsigned r = u + 0x7FFFu + ((u >> 16) & 1u);
  return (unsigned short)(r >> 16);
}
__device__ inline float bf2f(unsigned short h) {
  return __uint_as_float(((unsigned)h) << 16);
}

// ---------- P0 fused: encpk (blocks 0..9215) + mprep (blocks 9216..9983) ----------
__global__ __launch_bounds__(256) void pre_kernel(const float* __restrict__ enc,
                                                  unsigned* __restrict__ encpk,
                                                  const int* __restrict__ mask,
                                                  float* __restrict__ mprep) {
  int bid = blockIdx.x;
  if (bid < 9216) {
    int h = bid * 256 + threadIdx.x;            // < 2359296
    f32x4 v = *(const f32x4*)(enc + (size_t)h * 4);
    unsigned lo = (unsigned)f2bf_rne(v[0]) | ((unsigned)f2bf_rne(v[1]) << 16);
    unsigned hi = (unsigned)f2bf_rne(v[2]) | ((unsigned)f2bf_rne(v[3]) << 16);
    uint2 o; o.x = lo; o.y = hi;
    *(uint2*)(encpk + (size_t)h * 2) = o;
  } else {
    int i = bid - 9216, t = threadIdx.x;
    int sum = 0;
    for (int j = t; j < 768; j += 256) sum += mask[i*768 + j];
    for (int off = 32; off; off >>= 1) sum += __shfl_down(sum, off, 64);
    __shared__ int part[4];
    __shared__ float inv_s;
    if ((t & 63) == 0) part[t >> 6] = sum;
    __syncthreads();
    if (t == 0) inv_s = 1.0f / (float)(part[0] + part[1] + part[2] + part[3]);
    __syncthreads();
    float inv = inv_s;
    for (int j = t; j < 768; j += 256) mprep[i*768 + j] = (float)mask[i*768 + j] * inv;
  }
}

// ---------- P1: per-node A (hi/lo bf16, b-interleaved) + Zej (fp32); 16 nodes/block ----------
// block 0 additionally packs W1 enc-rows (wpk) and w2pad.
__global__ __launch_bounds__(256) void prep_kernel(const float* __restrict__ seq,
                                                   const float* __restrict__ W1,
                                                   const float* __restrict__ b1,
                                                   const float* __restrict__ W2,
                                                   unsigned* __restrict__ apk2,
                                                   float* __restrict__ zej,
                                                   unsigned* __restrict__ wpk,
                                                   float* __restrict__ w2pad) {
  const int bi0 = blockIdx.x * 16;
  __shared__ float sq[16][64];
  for (int q = threadIdx.x; q < 16*64; q += 256)
    sq[q >> 6][q & 63] = seq[bi0*64 + q];
  __syncthreads();
  const int c = threadIdx.x;
  if (c < 144) {
    float accA[16], accZ[16];
#pragma unroll
    for (int n = 0; n < 16; ++n) { accA[n] = b1[c]; accZ[n] = 0.f; }
#pragma unroll 4
    for (int u = 0; u < 64; ++u) {
      float wa = W1[u*144 + c];
      float wz = W1[(64 + u)*144 + c];
#pragma unroll
      for (int n = 0; n < 16; ++n) {
        float s = sq[n][u];
        accA[n] = fmaf(s, wa, accA[n]);
        accZ[n] = fmaf(s, wz, accZ[n]);
      }
    }
#pragma unroll
    for (int n = 0; n < 16; ++n) {
      int bi = bi0 + n;
      int b = (bi >= 768) ? 1 : 0;
      int nr = bi - b*768;
      unsigned short hi = f2bf_rne(accA[n]);
      unsigned short lo = f2bf_rne(accA[n] - bf2f(hi));
      apk2[(nr*160 + c)*2 + b] = (unsigned)hi | ((unsigned)lo << 16);
      zej[bi*160 + c] = accZ[n];
    }
  } else if (c < 160) {
#pragma unroll
    for (int n = 0; n < 16; ++n) {
      int bi = bi0 + n;
      int b = (bi >= 768) ? 1 : 0;
      int nr = bi - b*768;
      apk2[(nr*160 + c)*2 + b] = 0u;
      zej[bi*160 + c] = 0.f;
    }
  }
  if (blockIdx.x == 0) {
    for (int g = threadIdx.x; g < 1440; g += 256) {
      if (g < 1280) {
        int ew = g & 3;
        int l = (g >> 2) & 63;
        int t = g >> 8;                 // c-tile 0..4
        int cc = t*32 + (l & 31);
        unsigned short h[2];
#pragma unroll
        for (int q = 0; q < 2; ++q) {
          int e = ew*2 + q;
          int koff = (l >> 5)*8 + e;    // k-channel 0..15
          float v = (cc < 144) ? W1[(128 + koff)*144 + cc] : 0.f;
          h[q] = f2bf_rne(v);
        }
        wpk[g] = (unsigned)h[0] | ((unsigned)h[1] << 16);
      } else {
        int cc = g - 1280;
        w2pad[cc] = (cc < 144) ? W2[cc] : 0.f;
      }
    }
  }
}

// ---------- edge kernel: per-wave DMA rings (depth 4), segmented reduction ----------
__global__ __launch_bounds__(320, 4) void edge_kernel(
    const unsigned* __restrict__ encpk, const uint2* __restrict__ apkp,
    const float* __restrict__ zej, const unsigned* __restrict__ wpk,
    const float* __restrict__ w2pad, const float* __restrict__ b2p,
    const float* __restrict__ mprep, float* __restrict__ s_out) {
  const int tid = threadIdx.x;
  const int lane = tid & 63;
  const int w = tid >> 6;          // c-tile 0..4
  const int jb = blockIdx.x;       // 0..23
  const int i0 = blockIdx.y * 24;  // 32 i-blocks
  const int l31 = lane & 31, lh = lane >> 5;
  const int jglob = jb*32 + l31;

  bf16x8 wfrag = ((const bf16x8*)wpk)[w*64 + lane];

  float w2own[16];
#pragma unroll
  for (int r = 0; r < 16; ++r)
    w2own[r] = w2pad[w*32 + (r & 3) + 8*(r >> 2) + 4*lh];

  // Zej C-inits (fp32, C/D layout), one per batch
  f32x16 Cz0, Cz1;
#pragma unroll
  for (int q = 0; q < 4; ++q) {
    f32x4 z0 = *(const f32x4*)&zej[(0*768 + jglob)*160 + w*32 + 4*lh + 8*q];
    f32x4 z1 = *(const f32x4*)&zej[(768   + jglob)*160 + w*32 + 4*lh + 8*q];
#pragma unroll
    for (int m = 0; m < 4; ++m) { Cz0[q*4 + m] = z0[m]; Cz1[q*4 + m] = z1[m]; }
  }

  // mprep preload (reduction phase then touches no global memory)
  float mp[4][2];
  if (tid < 192) {
    const int j = tid & 31, g6 = tid >> 5;
#pragma unroll
    for (int s = 0; s < 4; ++s) {
      int i1 = i0 + s*6 + (g6 >> 1);
      mp[s][0] = mprep[i1*768 + jb*32 + j];
      mp[s][1] = mprep[(i1 + 3)*768 + jb*32 + j];
    }
  } else {
#pragma unroll
    for (int s = 0; s < 4; ++s) { mp[s][0] = 0.f; mp[s][1] = 0.f; }
  }

  bf16x8 ones;
#pragma unroll
  for (int e = 0; e < 8; ++e) ones[e] = 0;
  if (lh == 0) { ones[0] = (short)0x3F80; ones[1] = (short)0x3F80; }

  __shared__ float pdot[5][2][12][32];               // 15 KB (one 6-i segment)
  __shared__ float scomb[192];                       // 0.75 KB
  __shared__ __align__(16) char lds_enc[5][6][1024]; // 30 KB per-wave rings
  const float b2 = *b2p;

  // drain prologue vmem so steady-state vmcnt counts are exact
  asm volatile("s_waitcnt vmcnt(0)" ::: "memory");
  __builtin_amdgcn_sched_barrier(0);

  uint2 apkv[6];

#define GLD_ENC(I, SLOT)                                                        \
  __builtin_amdgcn_global_load_lds(                                            \
      (const __attribute__((address_space(1))) unsigned*)(encpk +              \
          (size_t)(i0 + (I))*6144 + jb*256 + l31*8 + lh*4),                     \
      (__attribute__((address_space(3))) unsigned*)&lds_enc[w][SLOT][0], 16, 0, 0)
#define APK(I, SLOT) apkv[SLOT] = apkp[(i0 + (I))*160 + w*32 + l31]

  // prologue: pairs 0..3 in flight (8 vmem ops)
  GLD_ENC(0, 0); APK(0, 0);
  GLD_ENC(1, 1); APK(1, 1);
  GLD_ENC(2, 2); APK(2, 2);
  GLD_ENC(3, 3); APK(3, 3);

  float sacc_t = 0.f;

  auto body = [&](int unit, int slot) {
    bf16x8 encf = *(const bf16x8*)(&lds_enc[w][slot][lane*16]);
    uint2 av = apkv[slot];

    f32x16 Ce0 = __builtin_amdgcn_mfma_f32_32x32x16_bf16(wfrag, encf, Cz0, 0, 0, 0);
    f32x16 Ce1 = __builtin_amdgcn_mfma_f32_32x32x16_bf16(wfrag, encf, Cz1, 0, 0, 0);

    bf16x8 af0, af1;
#pragma unroll
    for (int e = 2; e < 8; ++e) { af0[e] = 0; af1[e] = 0; }
    *(unsigned*)&af0 = av.x;   // hi|lo bf16 pair -> elems 0,1
    *(unsigned*)&af1 = av.y;

    f32x16 Cb0 = __builtin_amdgcn_mfma_f32_32x32x16_bf16(af0, ones, Ce0, 0, 0, 0);
    f32x16 Cb1 = __builtin_amdgcn_mfma_f32_32x32x16_bf16(af1, ones, Ce1, 0, 0, 0);

    // dot with leaky via h = 0.505z + 0.495|z|  (|.| is a free input modifier)
    float ta0[2] = {0.f, 0.f}, tb0[2] = {0.f, 0.f};
    float ta1[2] = {0.f, 0.f}, tb1[2] = {0.f, 0.f};
#pragma unroll
    for (int r = 0; r < 16; ++r) {
      float z0 = Cb0[r], z1 = Cb1[r];
      ta0[r & 1] = fmaf(z0, w2own[r], ta0[r & 1]);
      tb0[r & 1] = fmaf(fabsf(z0), w2own[r], tb0[r & 1]);
      ta1[r & 1] = fmaf(z1, w2own[r], ta1[r & 1]);
      tb1[r & 1] = fmaf(fabsf(z1), w2own[r], tb1[r & 1]);
    }
    float dp0 = 0.505f*(ta0[0] + ta0[1]) + 0.495f*(tb0[0] + tb0[1]);
    float dp1 = 0.505f*(ta1[0] + ta1[1]) + 0.495f*(tb1[0] + tb1[1]);
    pdot[w][lh][unit + 0][l31] = dp0;
    pdot[w][lh][unit + 1][l31] = dp1;
  };

#define STEP(IL, VM)                                                            \
  do {                                                                          \
    if ((IL) < 20) { GLD_ENC((IL) + 4, ((IL) + 4) % 6); APK((IL) + 4, ((IL) + 4) % 6); } \
    asm volatile("s_waitcnt vmcnt(" #VM ")" ::: "memory");                      \
    __builtin_amdgcn_sched_barrier(0);                                          \
    body(((IL) % 6) * 2, (IL) % 6);                                             \
  } while (0)

#define REDUCE(S, LAST)                                                         \
  do {                                                                          \
    asm volatile("s_waitcnt lgkmcnt(0)" ::: "memory");                          \
    __builtin_amdgcn_sched_barrier(0);                                          \
    __builtin_amdgcn_s_barrier();                                               \
    if (tid < 192) {                                                            \
      const int j = tid & 31, g6 = tid >> 5;                                    \
      float s1 = 0.f, s2 = 0.f;                                                 \
      _Pragma("unroll")                                                         \
      for (int w5 = 0; w5 < 5; ++w5) {                                          \
        s1 += pdot[w5][0][g6][j] + pdot[w5][1][g6][j];                          \
        s2 += pdot[w5][0][g6 + 6][j] + pdot[w5][1][g6 + 6][j];                  \
      }                                                                         \
      float wv1 = s1 + b2; wv1 = fmaxf(wv1, 0.01f*wv1);                         \
      float wv2 = s2 + b2; wv2 = fmaxf(wv2, 0.01f*wv2);                         \
      sacc_t = fmaf(mp[S][0], wv1, sacc_t);                                     \
      sacc_t = fmaf(mp[S][1], wv2, sacc_t);                                     \
    }                                                                           \
    if (!(LAST)) {                                                              \
      asm volatile("s_waitcnt lgkmcnt(0)" ::: "memory");                        \
      __builtin_amdgcn_sched_barrier(0);                                        \
      __builtin_amdgcn_s_barrier();                                             \
    }                                                                           \
  } while (0)

  STEP(0, 8);  STEP(1, 8);  STEP(2, 8);  STEP(3, 8);  STEP(4, 8);  STEP(5, 8);
  REDUCE(0, 0);
  STEP(6, 8);  STEP(7, 8);  STEP(8, 8);  STEP(9, 8);  STEP(10, 8); STEP(11, 8);
  REDUCE(1, 0);
  STEP(12, 8); STEP(13, 8); STEP(14, 8); STEP(15, 8); STEP(16, 8); STEP(17, 8);
  REDUCE(2, 0);
  STEP(18, 8); STEP(19, 8); STEP(20, 6); STEP(21, 4); STEP(22, 2); STEP(23, 0);
  REDUCE(3, 1);
#undef STEP
#undef REDUCE
#undef GLD_ENC
#undef APK

  if (tid < 192) scomb[tid] = sacc_t;
  __syncthreads();
  if (tid < 64) {
    const int b = tid >> 5, j = tid & 31;
    float tot = scomb[b*32 + j] + scomb[(b + 2)*32 + j] + scomb[(b + 4)*32 + j];
    atomicAdd(&s_out[b*768 + jb*32 + j], tot);
  }
}

// ---------- seq' = s * seq ----------
__global__ __launch_bounds__(256) void scale_kernel(const float* __restrict__ s,
                                                    const float* __restrict__ seq_in,
                                                    float* __restrict__ seq_out) {
  int idx = blockIdx.x * 256 + threadIdx.x;
  seq_out[idx] = s[idx >> 6] * seq_in[idx];
}

extern "C" void kernel_launch(void* const* d_in, const int* in_sizes, int n_in,
                              void* d_out, int out_size, void* d_ws, size_t ws_size,
                              hipStream_t stream) {
  const float* seq  = (const float*)d_in[0];
  const float* enc  = (const float*)d_in[1];
  const int*   mask = (const int*)d_in[2];
  const float* W11  = (const float*)d_in[3];
  const float* b11  = (const float*)d_in[4];
  const float* W12  = (const float*)d_in[5];
  const float* b12  = (const float*)d_in[6];
  const float* W21  = (const float*)d_in[7];
  const float* b21  = (const float*)d_in[8];
  const float* W22  = (const float*)d_in[9];
  const float* b22  = (const float*)d_in[10];
  float* out = (float*)d_out;

  float* ws = (float*)d_ws;
  size_t off = 0;
  float* mprep = ws + off;                 off += 768*768;
  unsigned* apk2 = (unsigned*)(ws + off);  off += 2*768*160;
  float* zej = ws + off;                   off += 2*768*160;
  unsigned* wpk = (unsigned*)(ws + off);   off += 1280;
  float* w2pad = ws + off;                 off += 160;
  float* sacc  = ws + off;                 off += 2*768;
  float* seq_mid = ws + off;               off += 2*768*64;
  unsigned* encpk = (unsigned*)(ws + off); off += 768*768*8;

  pre_kernel<<<9984, 256, 0, stream>>>(enc, encpk, mask, mprep);

  // hop 1
  prep_kernel<<<96, 256, 0, stream>>>(seq, W11, b11, W12, apk2, zej, wpk, w2pad);
  hipMemsetAsync(sacc, 0, 1536*sizeof(float), stream);
  edge_kernel<<<dim3(24, 32), 320, 0, stream>>>(encpk, (const uint2*)apk2, zej, wpk,
                                                w2pad, b12, mprep, sacc);
  scale_kernel<<<384, 256, 0, stream>>>(sacc, seq, seq_mid);

  // hop 2
  prep_kernel<<<96, 256, 0, stream>>>(seq_mid, W21, b21, W22, apk2, zej, wpk, w2pad);
  hipMemsetAsync(sacc, 0, 1536*sizeof(float), stream);
  edge_kernel<<<dim3(24, 32), 320, 0, stream>>>(encpk, (const uint2*)apk2, zej, wpk,
                                                w2pad, b22, mprep, sacc);
  scale_kernel<<<384, 256, 0, stream>>>(sacc, seq_mid, out);
}